// Round 4
// baseline (92.761 us; speedup 1.0000x reference)
//
#include <hip/hip_runtime.h>
#include <hip/hip_bf16.h>

#define VDIM 20
#define NPAIR 190
#define EMB 64
#define ATT 32
#define ERS 68   // ls_e row stride in floats (272B: 16B-aligned, bank=(4i+c)%32)

typedef __attribute__((ext_vector_type(8))) short bf16x8;   // MFMA A/B frag
typedef __attribute__((ext_vector_type(4))) float f32x4;    // MFMA acc / packed f32

union AFrag { bf16x8 v; unsigned u[4]; };

__device__ __forceinline__ unsigned pk_bf16(float a, float b) {
    __hip_bfloat162 h = __float22bfloat162_rn(make_float2(a, b));  // v_cvt_pk_bf16_f32
    unsigned r;
    __builtin_memcpy(&r, &h, sizeof(r));
    return r;
}

__device__ __forceinline__ short f2bf(float f) {               // cold fallback only
    unsigned u = __builtin_bit_cast(unsigned, f);
    u += 0x7fffu + ((u >> 16) & 1u);
    return (short)(u >> 16);
}

// ---- prep: W1 (32x64 f32) -> bf16 MFMA B-fragments in per-lane load order ----
__global__ void w1_prep(const float* __restrict__ w1, ushort* __restrict__ ws)
{
    int t    = threadIdx.x;          // 256 threads = 4 frags x 64 lanes
    int frag = t >> 6, lane = t & 63;
    int n  = (lane & 15) + 16 * (frag >> 1);          // att col
    int kb = (frag & 1) * 32 + (lane >> 4) * 8;       // k base
    const float* src = w1 + n * EMB + kb;
    uint4 o;
    o.x = pk_bf16(src[0], src[1]);
    o.y = pk_bf16(src[2], src[3]);
    o.z = pk_bf16(src[4], src[5]);
    o.w = pk_bf16(src[6], src[7]);
    reinterpret_cast<uint4*>(ws)[t] = o;
}

__global__ __launch_bounds__(256, 5)
void afm_fwd(const int* __restrict__ feats, const float* __restrict__ fvals,
             const float* __restrict__ emb, const float* __restrict__ btab,
             const float* __restrict__ gbias, const float* __restrict__ w1,
             const float* __restrict__ b1, const float* __restrict__ w2,
             const float* __restrict__ pw, const ushort* __restrict__ wsP,
             float* __restrict__ out)
{
    __shared__ __align__(16) float ls_e[VDIM * ERS];  // row-major e[i][d]
    __shared__ float ls_s[192];
    __shared__ float ls_red[3][4];

    const int tid  = threadIdx.x;
    const int wv   = tid >> 6;
    const int lane = tid & 63;
    const int g    = lane >> 4;
    const int a0   = lane & 15;
    const int b    = blockIdx.x;

    // ---- B fragments: 4 coalesced 16B loads from prepped ws (issue first) ----
    bf16x8 bv[2][2];
    if (wsP) {
        #pragma unroll
        for (int nt = 0; nt < 2; ++nt)
            #pragma unroll
            for (int ks = 0; ks < 2; ++ks)
                bv[nt][ks] = reinterpret_cast<const bf16x8*>(wsP)[(nt*2+ks)*64 + lane];
    } else {
        #pragma unroll
        for (int nt = 0; nt < 2; ++nt)
            #pragma unroll
            for (int ks = 0; ks < 2; ++ks) {
                const float* wp = w1 + (a0 + 16*nt) * EMB + ks*32 + g*8;
                #pragma unroll
                for (int e = 0; e < 8; ++e) bv[nt][ks][e] = f2bf(wp[e]);
            }
    }

    // ---- small shared vectors (global, L1/L2-hot after first blocks) ----
    float b1v0 = b1[a0], b1v1 = b1[a0 + 16];
    float w2v0 = w2[a0], w2v1 = w2[a0 + 16];
    f32x4 pw4[2][2];
    #pragma unroll
    for (int ks = 0; ks < 2; ++ks)
        #pragma unroll
        for (int h = 0; h < 2; ++h)
            pw4[ks][h] = *reinterpret_cast<const f32x4*>(pw + ks*32 + g*8 + 4*h);

    // ---- per-sample features/values in registers, shfl-broadcast ----
    int ff = 0; float vv = 0.f;
    if (lane < VDIM) { ff = feats[b * VDIM + lane]; vv = fvals[b * VDIM + lane]; }

    float fbsum = 0.f, gbv = 0.f;
    if (wv == 0) {
        float fbv = (lane < VDIM) ? btab[ff] * vv : 0.f;
        #pragma unroll
        for (int off = 32; off; off >>= 1) fbv += __shfl_xor(fbv, off);
        fbsum = fbv;
        if (lane == 0) gbv = gbias[0];
    }

    // ---- pair decode for this lane's 3 A-row slots ----
    int ia[3], ja[3];
    #pragma unroll
    for (int mt = 0; mt < 3; ++mt) {
        int p = wv * 48 + mt * 16 + a0;
        if (p >= NPAIR) p = 0;
        int i = 0, rem = p;
        while (rem >= VDIM - 1 - i) { rem -= VDIM - 1 - i; ++i; }
        ia[mt] = i; ja[mt] = i + 1 + rem;
    }

    // ---- gather: wave wv stages rows 5wv..5wv+4, coalesced 256B each ----
    #pragma unroll
    for (int r = 0; r < 5; ++r) {
        int   row = wv * 5 + r;
        int   fI  = __shfl(ff, row);
        float vI  = __shfl(vv, row);
        ls_e[row * ERS + lane] = emb[(size_t)fI * EMB + lane] * vI;
    }
    __syncthreads();

    // ---- main: packed products -> cvt_pk bf16 A-frags -> MFMA; fold s_p ----
    f32x4 acc[3][2];
    #pragma unroll
    for (int mt = 0; mt < 3; ++mt)
        #pragma unroll
        for (int nt = 0; nt < 2; ++nt)
            acc[mt][nt] = (f32x4){0.f, 0.f, 0.f, 0.f};
    f32x4 sp4[3] = {(f32x4){0,0,0,0}, (f32x4){0,0,0,0}, (f32x4){0,0,0,0}};

    #pragma unroll
    for (int ks = 0; ks < 2; ++ks) {
        AFrag av[3];
        #pragma unroll
        for (int mt = 0; mt < 3; ++mt) {
            const f32x4* ei = reinterpret_cast<const f32x4*>(ls_e + ia[mt]*ERS + ks*32 + g*8);
            const f32x4* ej = reinterpret_cast<const f32x4*>(ls_e + ja[mt]*ERS + ks*32 + g*8);
            #pragma unroll
            for (int h = 0; h < 2; ++h) {
                f32x4 prod = ei[h] * ej[h];                 // ds_read_b128 x2 + pk_mul
                sp4[mt] += prod * pw4[ks][h];               // pk_fma
                av[mt].u[h*2+0] = pk_bf16(prod[0], prod[1]);
                av[mt].u[h*2+1] = pk_bf16(prod[2], prod[3]);
            }
        }
        #pragma unroll
        for (int mt = 0; mt < 3; ++mt)
            #pragma unroll
            for (int nt = 0; nt < 2; ++nt)
                acc[mt][nt] = __builtin_amdgcn_mfma_f32_16x16x32_bf16(
                                  av[mt].v, bv[nt][ks], acc[mt][nt], 0, 0, 0);
    }

    // ---- s_p publish ----
    #pragma unroll
    for (int mt = 0; mt < 3; ++mt) {
        float s = sp4[mt][0] + sp4[mt][1] + sp4[mt][2] + sp4[mt][3];
        s += __shfl_xor(s, 16);
        s += __shfl_xor(s, 32);
        if (g == 0) ls_s[wv * 48 + mt * 16 + a0] = s;
    }
    __syncthreads();

    // ---- logits: w2 . relu(h + b1); C: col=lane&15, row=(lane>>4)*4+reg ----
    float lg[3][4];
    #pragma unroll
    for (int mt = 0; mt < 3; ++mt)
        #pragma unroll
        for (int r = 0; r < 4; ++r) {
            float c = fmaxf(acc[mt][0][r] + b1v0, 0.f) * w2v0
                    + fmaxf(acc[mt][1][r] + b1v1, 0.f) * w2v1;
            c += __shfl_xor(c, 1);
            c += __shfl_xor(c, 2);
            c += __shfl_xor(c, 4);
            c += __shfl_xor(c, 8);
            lg[mt][r] = c;
        }

    // ---- softmax across 190 pairs (cross-wave via LDS) ----
    float m = -3.4e38f;
    #pragma unroll
    for (int mt = 0; mt < 3; ++mt)
        #pragma unroll
        for (int r = 0; r < 4; ++r) {
            int p = wv * 48 + mt * 16 + g * 4 + r;
            if (p < NPAIR) m = fmaxf(m, lg[mt][r]);
        }
    #pragma unroll
    for (int off = 32; off; off >>= 1) m = fmaxf(m, __shfl_xor(m, off));
    if (lane == 0) ls_red[0][wv] = m;
    __syncthreads();

    float gm = fmaxf(fmaxf(ls_red[0][0], ls_red[0][1]),
                     fmaxf(ls_red[0][2], ls_red[0][3]));
    float num = 0.f, den = 0.f;
    #pragma unroll
    for (int mt = 0; mt < 3; ++mt)
        #pragma unroll
        for (int r = 0; r < 4; ++r) {
            int p = wv * 48 + mt * 16 + g * 4 + r;
            if (p < NPAIR) {
                float wgt = __expf(lg[mt][r] - gm);
                num = fmaf(wgt, ls_s[p], num);
                den += wgt;
            }
        }
    #pragma unroll
    for (int off = 32; off; off >>= 1) {
        num += __shfl_xor(num, off);
        den += __shfl_xor(den, off);
    }
    if (lane == 0) { ls_red[1][wv] = num; ls_red[2][wv] = den; }
    __syncthreads();

    if (tid == 0) {
        float N = ls_red[1][0] + ls_red[1][1] + ls_red[1][2] + ls_red[1][3];
        float D = ls_red[2][0] + ls_red[2][1] + ls_red[2][2] + ls_red[2][3];
        out[b] = N / D + fbsum + gbv;
    }
}

extern "C" void kernel_launch(void* const* d_in, const int* in_sizes, int n_in,
                              void* d_out, int out_size, void* d_ws, size_t ws_size,
                              hipStream_t stream)
{
    const int*   feats = (const int*)  d_in[0];
    const float* fvals = (const float*)d_in[1];
    const float* emb   = (const float*)d_in[2];
    const float* btab  = (const float*)d_in[3];
    const float* gb    = (const float*)d_in[4];
    const float* w1    = (const float*)d_in[5];
    const float* b1    = (const float*)d_in[6];
    const float* w2    = (const float*)d_in[7];
    const float* pw    = (const float*)d_in[8];
    float*       out   = (float*)d_out;

    const int B = in_sizes[0] / VDIM;
    ushort* wsP = (ws_size >= 4096) ? (ushort*)d_ws : nullptr;
    if (wsP) w1_prep<<<1, 256, 0, stream>>>(w1, wsP);
    afm_fwd<<<B, 256, 0, stream>>>(feats, fvals, emb, btab, gb,
                                   w1, b1, w2, pw, wsP, out);
}

// Round 5
// 70.532 us; speedup vs baseline: 1.3151x; 1.3151x over previous
//
#include <hip/hip_runtime.h>
#include <hip/hip_bf16.h>

#define VDIM 20
#define NPAIR 190
#define EMB 64
#define ATT 32
#define ERS 68   // ls_e row stride in floats (272B: 16B-aligned; rows i,i+8 share banks, <=3-way)

typedef __attribute__((ext_vector_type(8))) short    bf16x8; // MFMA A/B frag
typedef __attribute__((ext_vector_type(4))) float    f32x4;  // MFMA acc / packed f32
typedef __attribute__((ext_vector_type(4))) unsigned u32x4;  // packed bf16 pairs

__device__ __forceinline__ unsigned pk_bf16(float a, float b) {
    __hip_bfloat162 h = __float22bfloat162_rn(make_float2(a, b));  // v_cvt_pk_bf16_f32
    unsigned r;
    __builtin_memcpy(&r, &h, sizeof(r));
    return r;
}

__device__ __forceinline__ short f2bf(float f) {               // cold fallback only
    unsigned u = __builtin_bit_cast(unsigned, f);
    u += 0x7fffu + ((u >> 16) & 1u);
    return (short)(u >> 16);
}

// ---- prep: W1 (32x64 f32) -> bf16 MFMA B-fragments in per-lane load order ----
__global__ void w1_prep(const float* __restrict__ w1, ushort* __restrict__ ws)
{
    int t    = threadIdx.x;          // 256 threads = 4 frags x 64 lanes
    int frag = t >> 6, lane = t & 63;
    int n  = (lane & 15) + 16 * (frag >> 1);          // att col
    int kb = (frag & 1) * 32 + (lane >> 4) * 8;       // k base
    const float* src = w1 + n * EMB + kb;
    uint4 o;
    o.x = pk_bf16(src[0], src[1]);
    o.y = pk_bf16(src[2], src[3]);
    o.z = pk_bf16(src[4], src[5]);
    o.w = pk_bf16(src[6], src[7]);
    reinterpret_cast<uint4*>(ws)[t] = o;
}

__global__ __launch_bounds__(256, 4)
void afm_fwd(const int* __restrict__ feats, const float* __restrict__ fvals,
             const float* __restrict__ emb, const float* __restrict__ btab,
             const float* __restrict__ gbias, const float* __restrict__ w1,
             const float* __restrict__ b1, const float* __restrict__ w2,
             const float* __restrict__ pw, const ushort* __restrict__ wsP,
             float* __restrict__ out)
{
    __shared__ __align__(16) float ls_e[VDIM * ERS];  // row-major e[i][d]
    __shared__ float ls_s[192];
    __shared__ float ls_red[3][4];

    const int tid  = threadIdx.x;
    const int wv   = tid >> 6;
    const int lane = tid & 63;
    const int g    = lane >> 4;
    const int a0   = lane & 15;
    const int b    = blockIdx.x;

    // ---- B fragments: 4 coalesced 16B loads from prepped ws (issue first) ----
    bf16x8 bv[2][2];
    if (wsP) {
        #pragma unroll
        for (int nt = 0; nt < 2; ++nt)
            #pragma unroll
            for (int ks = 0; ks < 2; ++ks)
                bv[nt][ks] = reinterpret_cast<const bf16x8*>(wsP)[(nt*2+ks)*64 + lane];
    } else {
        #pragma unroll
        for (int nt = 0; nt < 2; ++nt)
            #pragma unroll
            for (int ks = 0; ks < 2; ++ks) {
                const float* wp = w1 + (a0 + 16*nt) * EMB + ks*32 + g*8;
                #pragma unroll
                for (int e = 0; e < 8; ++e) bv[nt][ks][e] = f2bf(wp[e]);
            }
    }

    // ---- small shared vectors (L1/L2-hot after first blocks) ----
    float b1v0 = b1[a0], b1v1 = b1[a0 + 16];
    float w2v0 = w2[a0], w2v1 = w2[a0 + 16];
    f32x4 pw4[2][2];
    #pragma unroll
    for (int ks = 0; ks < 2; ++ks)
        #pragma unroll
        for (int h = 0; h < 2; ++h)
            pw4[ks][h] = *reinterpret_cast<const f32x4*>(pw + ks*32 + g*8 + 4*h);

    // ---- per-sample features/values in registers, shfl-broadcast ----
    int ff = 0; float vv = 0.f;
    if (lane < VDIM) { ff = feats[b * VDIM + lane]; vv = fvals[b * VDIM + lane]; }

    float fbsum = 0.f, gbv = 0.f;
    if (wv == 0) {
        float fbv = (lane < VDIM) ? btab[ff] * vv : 0.f;
        #pragma unroll
        for (int off = 32; off; off >>= 1) fbv += __shfl_xor(fbv, off);
        fbsum = fbv;
        if (lane == 0) gbv = gbias[0];
    }

    // ---- pair decode for this lane's 3 A-row slots ----
    int ia[3], ja[3];
    #pragma unroll
    for (int mt = 0; mt < 3; ++mt) {
        int p = wv * 48 + mt * 16 + a0;
        if (p >= NPAIR) p = 0;
        int i = 0, rem = p;
        while (rem >= VDIM - 1 - i) { rem -= VDIM - 1 - i; ++i; }
        ia[mt] = i; ja[mt] = i + 1 + rem;
    }

    // ---- gather: wave wv stages rows 5wv..5wv+4, coalesced 256B each ----
    #pragma unroll
    for (int r = 0; r < 5; ++r) {
        int   row = wv * 5 + r;
        int   fI  = __shfl(ff, row);
        float vI  = __shfl(vv, row);
        ls_e[row * ERS + lane] = emb[(size_t)fI * EMB + lane] * vI;
    }
    __syncthreads();

    // ---- main: packed products -> cvt_pk bf16 A-frags -> MFMA; fold s_p ----
    f32x4 acc[3][2];
    #pragma unroll
    for (int mt = 0; mt < 3; ++mt)
        #pragma unroll
        for (int nt = 0; nt < 2; ++nt)
            acc[mt][nt] = (f32x4){0.f, 0.f, 0.f, 0.f};
    f32x4 sp4[3] = {(f32x4){0,0,0,0}, (f32x4){0,0,0,0}, (f32x4){0,0,0,0}};

    #pragma unroll
    for (int ks = 0; ks < 2; ++ks) {
        bf16x8 av[3];
        #pragma unroll
        for (int mt = 0; mt < 3; ++mt) {
            const f32x4* ei = reinterpret_cast<const f32x4*>(ls_e + ia[mt]*ERS + ks*32 + g*8);
            const f32x4* ej = reinterpret_cast<const f32x4*>(ls_e + ja[mt]*ERS + ks*32 + g*8);
            f32x4 p0 = ei[0] * ej[0];                   // ds_read_b128 x4 + v_pk_mul x2
            f32x4 p1 = ei[1] * ej[1];
            sp4[mt] += p0 * pw4[ks][0];                 // v_pk_fma x2
            sp4[mt] += p1 * pw4[ks][1];
            u32x4 aw;
            aw[0] = pk_bf16(p0[0], p0[1]);              // v_cvt_pk_bf16_f32 x4
            aw[1] = pk_bf16(p0[2], p0[3]);
            aw[2] = pk_bf16(p1[0], p1[1]);
            aw[3] = pk_bf16(p1[2], p1[3]);
            av[mt] = __builtin_bit_cast(bf16x8, aw);
        }
        #pragma unroll
        for (int mt = 0; mt < 3; ++mt)
            #pragma unroll
            for (int nt = 0; nt < 2; ++nt)
                acc[mt][nt] = __builtin_amdgcn_mfma_f32_16x16x32_bf16(
                                  av[mt], bv[nt][ks], acc[mt][nt], 0, 0, 0);
    }

    // ---- s_p publish ----
    #pragma unroll
    for (int mt = 0; mt < 3; ++mt) {
        float s = sp4[mt][0] + sp4[mt][1] + sp4[mt][2] + sp4[mt][3];
        s += __shfl_xor(s, 16);
        s += __shfl_xor(s, 32);
        if (g == 0) ls_s[wv * 48 + mt * 16 + a0] = s;
    }
    __syncthreads();

    // ---- logits: w2 . relu(h + b1); C: col=lane&15, row=(lane>>4)*4+reg ----
    float lg[3][4];
    #pragma unroll
    for (int mt = 0; mt < 3; ++mt)
        #pragma unroll
        for (int r = 0; r < 4; ++r) {
            float c = fmaxf(acc[mt][0][r] + b1v0, 0.f) * w2v0
                    + fmaxf(acc[mt][1][r] + b1v1, 0.f) * w2v1;
            c += __shfl_xor(c, 1);
            c += __shfl_xor(c, 2);
            c += __shfl_xor(c, 4);
            c += __shfl_xor(c, 8);
            lg[mt][r] = c;
        }

    // ---- softmax across 190 pairs (cross-wave via LDS) ----
    float m = -3.4e38f;
    #pragma unroll
    for (int mt = 0; mt < 3; ++mt)
        #pragma unroll
        for (int r = 0; r < 4; ++r) {
            int p = wv * 48 + mt * 16 + g * 4 + r;
            if (p < NPAIR) m = fmaxf(m, lg[mt][r]);
        }
    #pragma unroll
    for (int off = 32; off; off >>= 1) m = fmaxf(m, __shfl_xor(m, off));
    if (lane == 0) ls_red[0][wv] = m;
    __syncthreads();

    float gm = fmaxf(fmaxf(ls_red[0][0], ls_red[0][1]),
                     fmaxf(ls_red[0][2], ls_red[0][3]));
    float num = 0.f, den = 0.f;
    #pragma unroll
    for (int mt = 0; mt < 3; ++mt)
        #pragma unroll
        for (int r = 0; r < 4; ++r) {
            int p = wv * 48 + mt * 16 + g * 4 + r;
            if (p < NPAIR) {
                float wgt = __expf(lg[mt][r] - gm);
                num = fmaf(wgt, ls_s[p], num);
                den += wgt;
            }
        }
    #pragma unroll
    for (int off = 32; off; off >>= 1) {
        num += __shfl_xor(num, off);
        den += __shfl_xor(den, off);
    }
    if (lane == 0) { ls_red[1][wv] = num; ls_red[2][wv] = den; }
    __syncthreads();

    if (tid == 0) {
        float N = ls_red[1][0] + ls_red[1][1] + ls_red[1][2] + ls_red[1][3];
        float D = ls_red[2][0] + ls_red[2][1] + ls_red[2][2] + ls_red[2][3];
        out[b] = N / D + fbsum + gbv;
    }
}

extern "C" void kernel_launch(void* const* d_in, const int* in_sizes, int n_in,
                              void* d_out, int out_size, void* d_ws, size_t ws_size,
                              hipStream_t stream)
{
    const int*   feats = (const int*)  d_in[0];
    const float* fvals = (const float*)d_in[1];
    const float* emb   = (const float*)d_in[2];
    const float* btab  = (const float*)d_in[3];
    const float* gb    = (const float*)d_in[4];
    const float* w1    = (const float*)d_in[5];
    const float* b1    = (const float*)d_in[6];
    const float* w2    = (const float*)d_in[7];
    const float* pw    = (const float*)d_in[8];
    float*       out   = (float*)d_out;

    const int B = in_sizes[0] / VDIM;
    ushort* wsP = (ws_size >= 4096) ? (ushort*)d_ws : nullptr;
    if (wsP) w1_prep<<<1, 256, 0, stream>>>(w1, wsP);
    afm_fwd<<<B, 256, 0, stream>>>(feats, fvals, emb, btab, gb,
                                   w1, b1, w2, pw, wsP, out);
}

// Round 6
// 60.925 us; speedup vs baseline: 1.5225x; 1.1577x over previous
//
#include <hip/hip_runtime.h>
#include <hip/hip_bf16.h>

#define VDIM 20
#define NPAIR 190
#define EMB 64
#define ATT 32
#define ERS 68   // ls_e row stride in floats (272B, 16B-aligned)

typedef __attribute__((ext_vector_type(8))) short    bf16x8; // MFMA A/B frag
typedef __attribute__((ext_vector_type(4))) float    f32x4;  // MFMA acc / packed f32
typedef __attribute__((ext_vector_type(4))) unsigned u32x4;  // packed bf16 pairs

__device__ __forceinline__ unsigned pk_bf16(float a, float b) {
    __hip_bfloat162 h = __float22bfloat162_rn(make_float2(a, b));  // v_cvt_pk_bf16_f32
    unsigned r;
    __builtin_memcpy(&r, &h, sizeof(r));
    return r;
}

__device__ __forceinline__ short f2bf(float f) {               // cold fallback only
    unsigned u = __builtin_bit_cast(unsigned, f);
    u += 0x7fffu + ((u >> 16) & 1u);
    return (short)(u >> 16);
}

// ---- prep: W1 (32x64 f32) -> bf16 MFMA A-fragments in per-lane load order ----
// frag t>>6 = mta*2+ks; lane holds row m=(lane&15)+16*mta, k=(ks*32)+(lane>>4)*8+e
__global__ void w1_prep(const float* __restrict__ w1, ushort* __restrict__ ws)
{
    int t    = threadIdx.x;          // 256 threads = 4 frags x 64 lanes
    int frag = t >> 6, lane = t & 63;
    int n  = (lane & 15) + 16 * (frag >> 1);          // att row
    int kb = (frag & 1) * 32 + (lane >> 4) * 8;       // k base
    const float* src = w1 + n * EMB + kb;
    uint4 o;
    o.x = pk_bf16(src[0], src[1]);
    o.y = pk_bf16(src[2], src[3]);
    o.z = pk_bf16(src[4], src[5]);
    o.w = pk_bf16(src[6], src[7]);
    reinterpret_cast<uint4*>(ws)[t] = o;
}

__global__ __launch_bounds__(256, 2)
void afm_fwd(const int* __restrict__ feats, const float* __restrict__ fvals,
             const float* __restrict__ emb, const float* __restrict__ btab,
             const float* __restrict__ gbias, const float* __restrict__ w1,
             const float* __restrict__ b1, const float* __restrict__ w2,
             const float* __restrict__ pw, const ushort* __restrict__ wsP,
             float* __restrict__ out)
{
    __shared__ __align__(16) float ls_e[VDIM * ERS];  // row-major e[i][d]
    __shared__ float ls_red[3][4];                    // [0]=max [1]=num [2]=den per wave

    const int tid  = threadIdx.x;
    const int wv   = tid >> 6;
    const int lane = tid & 63;
    const int g    = lane >> 4;
    const int a0   = lane & 15;
    const int b    = blockIdx.x;

    // ---- A-frags (W1): 4 coalesced 16B loads from prepped ws ----
    bf16x8 aw[2][2];                                  // [mta][ks]
    if (wsP) {
        #pragma unroll
        for (int mta = 0; mta < 2; ++mta)
            #pragma unroll
            for (int ks = 0; ks < 2; ++ks)
                aw[mta][ks] = reinterpret_cast<const bf16x8*>(wsP)[(mta*2+ks)*64 + lane];
    } else {
        #pragma unroll
        for (int mta = 0; mta < 2; ++mta)
            #pragma unroll
            for (int ks = 0; ks < 2; ++ks) {
                const float* wp = w1 + (a0 + 16*mta) * EMB + ks*32 + g*8;
                #pragma unroll
                for (int e = 0; e < 8; ++e) aw[mta][ks][e] = f2bf(wp[e]);
            }
    }

    // ---- A-frag for pred_w: row 0 = pw, rows 1..15 = 0 -> s_p in C row 0 ----
    bf16x8 apw[2];
    #pragma unroll
    for (int ks = 0; ks < 2; ++ks) {
        const float* pp = pw + ks*32 + g*8;
        u32x4 t;
        t[0] = pk_bf16(pp[0], pp[1]);
        t[1] = pk_bf16(pp[2], pp[3]);
        t[2] = pk_bf16(pp[4], pp[5]);
        t[3] = pk_bf16(pp[6], pp[7]);
        if (a0 != 0) t = (u32x4){0u, 0u, 0u, 0u};
        apw[ks] = __builtin_bit_cast(bf16x8, t);
    }

    // ---- b1/w2 slices for this lane's att rows: att = mta*16 + g*4 + r ----
    f32x4 b1v[2], w2v[2];
    #pragma unroll
    for (int mta = 0; mta < 2; ++mta) {
        b1v[mta] = *reinterpret_cast<const f32x4*>(b1 + mta*16 + g*4);
        w2v[mta] = *reinterpret_cast<const f32x4*>(w2 + mta*16 + g*4);
    }

    // ---- per-sample features/values, first-order bias (wave 0) ----
    int ff = 0; float vv = 0.f;
    if (lane < VDIM) { ff = feats[b * VDIM + lane]; vv = fvals[b * VDIM + lane]; }

    float fbsum = 0.f, gbv = 0.f;
    if (wv == 0) {
        float fbv = (lane < VDIM) ? btab[ff] * vv : 0.f;
        #pragma unroll
        for (int off = 32; off; off >>= 1) fbv += __shfl_xor(fbv, off);
        fbsum = fbv;
        if (lane == 0) gbv = gbias[0];
    }

    // ---- pair decode: lane column a0 owns pairs wv*48 + ntp*16 + a0 ----
    int ia[3], ja[3];
    #pragma unroll
    for (int ntp = 0; ntp < 3; ++ntp) {
        int p = wv * 48 + ntp * 16 + a0;
        if (p >= NPAIR) p = 0;
        int i = 0, rem = p;
        while (rem >= VDIM - 1 - i) { rem -= VDIM - 1 - i; ++i; }
        ia[ntp] = i; ja[ntp] = i + 1 + rem;
    }

    // ---- gather: wave wv stages rows 5wv..5wv+4, coalesced 256B each ----
    #pragma unroll
    for (int r = 0; r < 5; ++r) {
        int   row = wv * 5 + r;
        int   fI  = __shfl(ff, row);
        float vI  = __shfl(vv, row);
        ls_e[row * ERS + lane] = emb[(size_t)fI * EMB + lane] * vI;
    }
    __syncthreads();

    // ---- main: B-frags = pair products (bf16), MFMA h^T and s ----
    f32x4 acc[3][2];                                  // [ntp][mta] : h^T tiles
    f32x4 accs[3];                                    // s tiles (row 0 valid)
    #pragma unroll
    for (int ntp = 0; ntp < 3; ++ntp) {
        acc[ntp][0] = (f32x4){0.f,0.f,0.f,0.f};
        acc[ntp][1] = (f32x4){0.f,0.f,0.f,0.f};
        accs[ntp]   = (f32x4){0.f,0.f,0.f,0.f};
    }

    #pragma unroll
    for (int ks = 0; ks < 2; ++ks) {
        bf16x8 bB[3];
        #pragma unroll
        for (int ntp = 0; ntp < 3; ++ntp) {
            const f32x4* ei = reinterpret_cast<const f32x4*>(ls_e + ia[ntp]*ERS + ks*32 + g*8);
            const f32x4* ej = reinterpret_cast<const f32x4*>(ls_e + ja[ntp]*ERS + ks*32 + g*8);
            f32x4 p0 = ei[0] * ej[0];                 // ds_read_b128 x4 + v_pk_mul x2
            f32x4 p1 = ei[1] * ej[1];
            u32x4 awv;
            awv[0] = pk_bf16(p0[0], p0[1]);           // v_cvt_pk_bf16_f32 x4
            awv[1] = pk_bf16(p0[2], p0[3]);
            awv[2] = pk_bf16(p1[0], p1[1]);
            awv[3] = pk_bf16(p1[2], p1[3]);
            bB[ntp] = __builtin_bit_cast(bf16x8, awv);
        }
        #pragma unroll
        for (int ntp = 0; ntp < 3; ++ntp) {
            acc[ntp][0] = __builtin_amdgcn_mfma_f32_16x16x32_bf16(aw[0][ks], bB[ntp], acc[ntp][0], 0, 0, 0);
            acc[ntp][1] = __builtin_amdgcn_mfma_f32_16x16x32_bf16(aw[1][ks], bB[ntp], acc[ntp][1], 0, 0, 0);
            accs[ntp]   = __builtin_amdgcn_mfma_f32_16x16x32_bf16(apw[ks],   bB[ntp], accs[ntp],   0, 0, 0);
        }
    }

    // ---- logits: in-lane sum over 8 att rows, then 2 shuffles over g ----
    float lg[3];
    #pragma unroll
    for (int ntp = 0; ntp < 3; ++ntp) {
        float t = 0.f;
        #pragma unroll
        for (int r = 0; r < 4; ++r) {
            t += fmaxf(acc[ntp][0][r] + b1v[0][r], 0.f) * w2v[0][r];
            t += fmaxf(acc[ntp][1][r] + b1v[1][r], 0.f) * w2v[1][r];
        }
        t += __shfl_xor(t, 16);
        t += __shfl_xor(t, 32);
        lg[ntp] = t;                                  // replicated over g
    }

    // ---- wave max (masked), cross-wave via LDS ----
    const float NEG = -3.4e38f;
    float m = NEG;
    #pragma unroll
    for (int ntp = 0; ntp < 3; ++ntp) {
        int p = wv * 48 + ntp * 16 + a0;
        if (p < NPAIR) m = fmaxf(m, lg[ntp]);
    }
    m = fmaxf(m, __shfl_xor(m, 1));
    m = fmaxf(m, __shfl_xor(m, 2));
    m = fmaxf(m, __shfl_xor(m, 4));
    m = fmaxf(m, __shfl_xor(m, 8));
    if (lane == 0) ls_red[0][wv] = m;
    __syncthreads();

    float gm = fmaxf(fmaxf(ls_red[0][0], ls_red[0][1]),
                     fmaxf(ls_red[0][2], ls_red[0][3]));

    // ---- num/den: s lives on g==0 lanes (C row 0); exact x1 counting ----
    float num = 0.f, den = 0.f;
    if (g == 0) {
        #pragma unroll
        for (int ntp = 0; ntp < 3; ++ntp) {
            int p = wv * 48 + ntp * 16 + a0;
            if (p < NPAIR) {
                float wgt = __expf(lg[ntp] - gm);
                num = fmaf(wgt, accs[ntp][0], num);
                den += wgt;
            }
        }
    }
    #pragma unroll
    for (int off = 32; off; off >>= 1) {
        num += __shfl_xor(num, off);
        den += __shfl_xor(den, off);
    }
    if (lane == 0) { ls_red[1][wv] = num; ls_red[2][wv] = den; }
    __syncthreads();

    if (tid == 0) {
        float N = ls_red[1][0] + ls_red[1][1] + ls_red[1][2] + ls_red[1][3];
        float D = ls_red[2][0] + ls_red[2][1] + ls_red[2][2] + ls_red[2][3];
        out[b] = N / D + fbsum + gbv;
    }
}

extern "C" void kernel_launch(void* const* d_in, const int* in_sizes, int n_in,
                              void* d_out, int out_size, void* d_ws, size_t ws_size,
                              hipStream_t stream)
{
    const int*   feats = (const int*)  d_in[0];
    const float* fvals = (const float*)d_in[1];
    const float* emb   = (const float*)d_in[2];
    const float* btab  = (const float*)d_in[3];
    const float* gb    = (const float*)d_in[4];
    const float* w1    = (const float*)d_in[5];
    const float* b1    = (const float*)d_in[6];
    const float* w2    = (const float*)d_in[7];
    const float* pw    = (const float*)d_in[8];
    float*       out   = (float*)d_out;

    const int B = in_sizes[0] / VDIM;
    ushort* wsP = (ws_size >= 4096) ? (ushort*)d_ws : nullptr;
    if (wsP) w1_prep<<<1, 256, 0, stream>>>(w1, wsP);
    afm_fwd<<<B, 256, 0, stream>>>(feats, fvals, emb, btab, gb,
                                   w1, b1, w2, pw, wsP, out);
}

// Round 7
// 33.810 us; speedup vs baseline: 2.7435x; 1.8019x over previous
//
#include <hip/hip_runtime.h>
#include <hip/hip_bf16.h>

#define VDIM 20
#define NPAIR 190
#define NT 12            // 12 pair-tiles of 16 (190 -> 192)
#define EMB 64
#define ATT 32
#define ERS 68           // ls_e row stride in floats (272B = 17*16B, b128-aligned)

typedef __attribute__((ext_vector_type(8))) short    bf16x8;
typedef __attribute__((ext_vector_type(4))) float    f32x4;
typedef __attribute__((ext_vector_type(4))) unsigned u32x4;

// ws layout: [0,4096) W1 A-frags | [4096,6144) pw A-frags | [6144,6912) pair offs
#define WS_APW  4096
#define WS_PTBL 6144
#define WS_NEED 8192

__device__ __forceinline__ unsigned pk_bf16(float a, float b) {
    __hip_bfloat162 h = __float22bfloat162_rn(make_float2(a, b));  // v_cvt_pk_bf16_f32
    unsigned r;
    __builtin_memcpy(&r, &h, sizeof(r));
    return r;
}

__device__ __forceinline__ short f2bf(float f) {               // fallback only
    unsigned u = __builtin_bit_cast(unsigned, f);
    u += 0x7fffu + ((u >> 16) & 1u);
    return (short)(u >> 16);
}

// ---- prep: W1 + pred_w -> bf16 A-fragments; pair (i,j) -> packed byte offsets ----
__global__ void prep(const float* __restrict__ w1, const float* __restrict__ pw,
                     unsigned char* __restrict__ ws)
{
    int t = threadIdx.x, lane = t & 63;
    {   // W1 frag (mta = t>>7, ks = (t>>6)&1): row m=(lane&15)+16*mta, k=ks*32+(lane>>4)*8+e
        int frag = t >> 6;
        int n  = (lane & 15) + 16 * (frag >> 1);
        int kb = (frag & 1) * 32 + (lane >> 4) * 8;
        const float* src = w1 + n * EMB + kb;
        uint4 o;
        o.x = pk_bf16(src[0], src[1]);
        o.y = pk_bf16(src[2], src[3]);
        o.z = pk_bf16(src[4], src[5]);
        o.w = pk_bf16(src[6], src[7]);
        reinterpret_cast<uint4*>(ws)[t] = o;
    }
    if (t < 128) {   // pred_w frag: row 0 = pw, rows 1..15 = 0
        int ks = t >> 6, a0 = lane & 15, g = lane >> 4;
        const float* pp = pw + ks * 32 + g * 8;
        uint4 o;
        o.x = pk_bf16(pp[0], pp[1]);
        o.y = pk_bf16(pp[2], pp[3]);
        o.z = pk_bf16(pp[4], pp[5]);
        o.w = pk_bf16(pp[6], pp[7]);
        if (a0 != 0) o = make_uint4(0u, 0u, 0u, 0u);
        reinterpret_cast<uint4*>(ws + WS_APW)[t] = o;
    }
    if (t < 192) {   // pair decode -> (i*272) | (j*272)<<16
        int p = (t < NPAIR) ? t : 0;
        int i = 0, rem = p;
        while (rem >= VDIM - 1 - i) { rem -= VDIM - 1 - i; ++i; }
        int j = i + 1 + rem;
        reinterpret_cast<unsigned*>(ws + WS_PTBL)[t] =
            (unsigned)(i * ERS * 4) | ((unsigned)(j * ERS * 4) << 16);
    }
}

__global__ __launch_bounds__(256, 2)
void afm_fwd(const int* __restrict__ feats, const float* __restrict__ fvals,
             const float* __restrict__ emb, const float* __restrict__ btab,
             const float* __restrict__ gbias, const float* __restrict__ w1,
             const float* __restrict__ b1, const float* __restrict__ w2,
             const float* __restrict__ pw, const unsigned char* __restrict__ wsP,
             float* __restrict__ out, int B)
{
    __shared__ __align__(16) float ls_e[4][VDIM * ERS];  // private slab per wave

    const int tid  = threadIdx.x;
    const int wv   = tid >> 6;
    const int lane = tid & 63;
    const int g    = lane >> 4;
    const int a0   = lane & 15;
    const int b    = blockIdx.x * 4 + wv;
    if (b >= B) return;                                  // no barriers below: safe

    // ---- per-sample features/values (issue loads early) ----
    int ff = 0; float vv = 0.f;
    if (lane < VDIM) { ff = feats[b * VDIM + lane]; vv = fvals[b * VDIM + lane]; }

    // ---- A-frags: W1 and pred_w from prepped ws ----
    bf16x8 aw[2][2], apw[2];
    if (wsP) {
        const bf16x8* wf = reinterpret_cast<const bf16x8*>(wsP);
        aw[0][0] = wf[0 * 64 + lane];
        aw[0][1] = wf[1 * 64 + lane];
        aw[1][0] = wf[2 * 64 + lane];
        aw[1][1] = wf[3 * 64 + lane];
        const bf16x8* pf = reinterpret_cast<const bf16x8*>(wsP + WS_APW);
        apw[0] = pf[lane];
        apw[1] = pf[64 + lane];
    } else {
        #pragma unroll
        for (int mta = 0; mta < 2; ++mta)
            #pragma unroll
            for (int ks = 0; ks < 2; ++ks) {
                const float* wp = w1 + (a0 + 16*mta) * EMB + ks*32 + g*8;
                #pragma unroll
                for (int e = 0; e < 8; ++e) aw[mta][ks][e] = f2bf(wp[e]);
            }
        #pragma unroll
        for (int ks = 0; ks < 2; ++ks) {
            const float* pp = pw + ks*32 + g*8;
            u32x4 t;
            t[0] = pk_bf16(pp[0], pp[1]);
            t[1] = pk_bf16(pp[2], pp[3]);
            t[2] = pk_bf16(pp[4], pp[5]);
            t[3] = pk_bf16(pp[6], pp[7]);
            if (a0 != 0) t = (u32x4){0u, 0u, 0u, 0u};
            apw[ks] = __builtin_bit_cast(bf16x8, t);
        }
    }

    // ---- b1/w2 slices for this lane's att rows: att = mta*16 + g*4 + r ----
    f32x4 b1v[2], w2v[2];
    #pragma unroll
    for (int mta = 0; mta < 2; ++mta) {
        b1v[mta] = *reinterpret_cast<const f32x4*>(b1 + mta*16 + g*4);
        w2v[mta] = *reinterpret_cast<const f32x4*>(w2 + mta*16 + g*4);
    }

    // ---- first-order bias: wave-local reduce ----
    float fbv = (lane < VDIM) ? btab[ff] * vv : 0.f;
    #pragma unroll
    for (int off = 32; off; off >>= 1) fbv += __shfl_xor(fbv, off);
    float gbv = gbias[0];

    // ---- gather all 20 rows (independent loads in flight, no barrier) ----
    float* ew = ls_e[wv];
    #pragma unroll
    for (int r = 0; r < VDIM; ++r) {
        int   fI = __shfl(ff, r);
        float vI = __shfl(vv, r);
        ew[r * ERS + lane] = emb[(size_t)fI * EMB + lane] * vI;
    }
    asm volatile("s_waitcnt lgkmcnt(0)" ::: "memory");   // writes landed (in-order DS)
    __builtin_amdgcn_wave_barrier();

    const unsigned* ptbl = wsP ? reinterpret_cast<const unsigned*>(wsP + WS_PTBL) : nullptr;

    // ---- main: 12 pair-tiles; softmax without max-subtract (|logit| << 1) ----
    float num = 0.f, den = 0.f;
    #pragma unroll 2
    for (int nt = 0; nt < NT; ++nt) {
        unsigned po;
        if (ptbl) {
            po = ptbl[nt * 16 + a0];
        } else {
            int p = nt * 16 + a0;
            if (p >= NPAIR) p = 0;
            int i = 0, rem = p;
            while (rem >= VDIM - 1 - i) { rem -= VDIM - 1 - i; ++i; }
            po = (unsigned)(i * ERS * 4) | ((unsigned)((i + 1 + rem) * ERS * 4) << 16);
        }
        const char* bi = (const char*)ew + (po & 0xffffu);
        const char* bj = (const char*)ew + (po >> 16);

        f32x4 acc0 = (f32x4){0.f,0.f,0.f,0.f};
        f32x4 acc1 = (f32x4){0.f,0.f,0.f,0.f};
        f32x4 accs = (f32x4){0.f,0.f,0.f,0.f};
        #pragma unroll
        for (int ks = 0; ks < 2; ++ks) {
            const f32x4* ei = reinterpret_cast<const f32x4*>(bi + ks*128 + g*32);
            const f32x4* ej = reinterpret_cast<const f32x4*>(bj + ks*128 + g*32);
            f32x4 p0 = ei[0] * ej[0];                    // ds_read_b128 x4, v_pk_mul x4
            f32x4 p1 = ei[1] * ej[1];
            u32x4 t;
            t[0] = pk_bf16(p0[0], p0[1]);                // v_cvt_pk_bf16_f32 x4
            t[1] = pk_bf16(p0[2], p0[3]);
            t[2] = pk_bf16(p1[0], p1[1]);
            t[3] = pk_bf16(p1[2], p1[3]);
            bf16x8 bB = __builtin_bit_cast(bf16x8, t);
            acc0 = __builtin_amdgcn_mfma_f32_16x16x32_bf16(aw[0][ks], bB, acc0, 0, 0, 0);
            acc1 = __builtin_amdgcn_mfma_f32_16x16x32_bf16(aw[1][ks], bB, acc1, 0, 0, 0);
            accs = __builtin_amdgcn_mfma_f32_16x16x32_bf16(apw[ks],   bB, accs, 0, 0, 0);
        }
        // logit for pair (nt, a0): in-lane over 8 att rows + 2 shuffles over g
        float tl = 0.f;
        #pragma unroll
        for (int r = 0; r < 4; ++r) {
            tl += fmaxf(acc0[r] + b1v[0][r], 0.f) * w2v[0][r];
            tl += fmaxf(acc1[r] + b1v[1][r], 0.f) * w2v[1][r];
        }
        tl += __shfl_xor(tl, 16);
        tl += __shfl_xor(tl, 32);
        // accumulate softmax numerator/denominator (s = accs[0], valid on g==0)
        bool valid = (nt < 11) | (a0 < 14);
        float w = valid ? __expf(tl) : 0.f;
        num = fmaf(w, accs[0], num);                     // only g==0 lanes meaningful
        den += w;
    }

    // ---- reduce num/den across a0 within the g==0 group ----
    num += __shfl_xor(num, 1);  den += __shfl_xor(den, 1);
    num += __shfl_xor(num, 2);  den += __shfl_xor(den, 2);
    num += __shfl_xor(num, 4);  den += __shfl_xor(den, 4);
    num += __shfl_xor(num, 8);  den += __shfl_xor(den, 8);

    if (lane == 0)
        out[b] = num / den + fbv + gbv;
}

extern "C" void kernel_launch(void* const* d_in, const int* in_sizes, int n_in,
                              void* d_out, int out_size, void* d_ws, size_t ws_size,
                              hipStream_t stream)
{
    const int*   feats = (const int*)  d_in[0];
    const float* fvals = (const float*)d_in[1];
    const float* emb   = (const float*)d_in[2];
    const float* btab  = (const float*)d_in[3];
    const float* gb    = (const float*)d_in[4];
    const float* w1    = (const float*)d_in[5];
    const float* b1    = (const float*)d_in[6];
    const float* w2    = (const float*)d_in[7];
    const float* pw    = (const float*)d_in[8];
    float*       out   = (float*)d_out;

    const int B = in_sizes[0] / VDIM;
    unsigned char* wsP = (ws_size >= WS_NEED) ? (unsigned char*)d_ws : nullptr;
    if (wsP) prep<<<1, 256, 0, stream>>>(w1, pw, wsP);
    afm_fwd<<<(B + 3) / 4, 256, 0, stream>>>(feats, fvals, emb, btab, gb,
                                             w1, b1, w2, pw, wsP, out, B);
}

// Round 9
// 29.155 us; speedup vs baseline: 3.1817x; 1.1597x over previous
//
#include <hip/hip_runtime.h>

#define VDIM 20
#define NPAIR 190
#define NT 12            // 12 pair-tiles of 16 (190 -> 192)
#define EMB 64
#define ERS2 72          // f16 row stride (144 B): rows rotate bank-quads, conflict-even

typedef __attribute__((ext_vector_type(8))) _Float16 f16x8;  // MFMA A/B frag (4 VGPR)
typedef __attribute__((ext_vector_type(4))) _Float16 f16x4;
typedef __attribute__((ext_vector_type(4))) float    f32x4;

__device__ __forceinline__ f16x8 pack8(f32x4 a, f32x4 b) {
    auto p0 = __builtin_amdgcn_cvt_pkrtz(a[0], a[1]);  // v_cvt_pkrtz_f16_f32
    auto p1 = __builtin_amdgcn_cvt_pkrtz(a[2], a[3]);
    auto p2 = __builtin_amdgcn_cvt_pkrtz(b[0], b[1]);
    auto p3 = __builtin_amdgcn_cvt_pkrtz(b[2], b[3]);
    f16x8 r;
    r[0] = p0[0]; r[1] = p0[1]; r[2] = p1[0]; r[3] = p1[1];
    r[4] = p2[0]; r[5] = p2[1]; r[6] = p3[0]; r[7] = p3[1];
    return r;
}

__global__ __launch_bounds__(256, 4)
void afm_fwd(const int* __restrict__ feats, const float* __restrict__ fvals,
             const float* __restrict__ emb, const float* __restrict__ btab,
             const float* __restrict__ gbias, const float* __restrict__ w1,
             const float* __restrict__ b1, const float* __restrict__ w2,
             const float* __restrict__ pw, float* __restrict__ out, int B)
{
    __shared__ __align__(16) _Float16 ls_e[4][VDIM * ERS2];  // 2.88 KB per wave

    const int tid  = threadIdx.x;
    const int wv   = tid >> 6;
    const int lane = tid & 63;
    const int g    = lane >> 4;
    const int a0   = lane & 15;
    const int b    = blockIdx.x * 4 + wv;
    if (b >= B) return;                                  // no barriers below: safe

    // ---- per-sample features/values (issue loads first) ----
    int ff = 0; float vv = 0.f;
    if (lane < VDIM) { ff = feats[b * VDIM + lane]; vv = fvals[b * VDIM + lane]; }

    // ---- A-frags in f16, built in-register from L2-hot tables ----
    // W1 frag: row m = a0 + 16*mta, k = ks*32 + g*8 + e
    f16x8 aw[2][2];
    #pragma unroll
    for (int mta = 0; mta < 2; ++mta)
        #pragma unroll
        for (int ks = 0; ks < 2; ++ks) {
            const f32x4* wp = reinterpret_cast<const f32x4*>(
                                  w1 + (a0 + 16*mta) * EMB + ks*32 + g*8);
            aw[mta][ks] = pack8(wp[0], wp[1]);
        }
    // pred_w frag: row 0 = pw, rows 1..15 = 0  -> s_p lands in C row 0 (g==0)
    f16x8 apw[2];
    {
        const f16x8 zz = {};
        #pragma unroll
        for (int ks = 0; ks < 2; ++ks) {
            const f32x4* pp = reinterpret_cast<const f32x4*>(pw + ks*32 + g*8);
            apw[ks] = (a0 == 0) ? pack8(pp[0], pp[1]) : zz;
        }
    }

    // ---- b1/w2 slices for this lane's att rows: att = mta*16 + g*4 + r ----
    f32x4 b1v[2], w2v[2];
    #pragma unroll
    for (int mta = 0; mta < 2; ++mta) {
        b1v[mta] = *reinterpret_cast<const f32x4*>(b1 + mta*16 + g*4);
        w2v[mta] = *reinterpret_cast<const f32x4*>(w2 + mta*16 + g*4);
    }

    // ---- first-order bias: wave-local reduce ----
    float fbv = (lane < VDIM) ? btab[ff] * vv : 0.f;
    #pragma unroll
    for (int off = 32; off; off >>= 1) fbv += __shfl_xor(fbv, off);
    const float gbv = gbias[0];

    // ---- gather: 5 passes x 4 rows; float4 load -> pkrtz -> ds_write_b64 ----
    _Float16* ew = ls_e[wv];
    #pragma unroll
    for (int q = 0; q < 5; ++q) {
        int   row = q * 4 + g;
        int   fI  = __shfl(ff, row);
        float vI  = __shfl(vv, row);
        f32x4 ev  = reinterpret_cast<const f32x4*>(emb + (size_t)fI * EMB)[a0];
        auto h0 = __builtin_amdgcn_cvt_pkrtz(ev[0] * vI, ev[1] * vI);
        auto h1 = __builtin_amdgcn_cvt_pkrtz(ev[2] * vI, ev[3] * vI);
        f16x4 hv;
        hv[0] = h0[0]; hv[1] = h0[1]; hv[2] = h1[0]; hv[3] = h1[1];
        *reinterpret_cast<f16x4*>(
            reinterpret_cast<char*>(ew) + row * (ERS2*2) + a0 * 8) = hv;
    }
    asm volatile("s_waitcnt lgkmcnt(0)" ::: "memory");   // DS in-order within wave
    __builtin_amdgcn_wave_barrier();

    // ---- main: 12 pair-tiles; softmax without max-subtract (|logit| << 1) ----
    float num = 0.f, den = 0.f;
    #pragma unroll 2
    for (int nt = 0; nt < NT; ++nt) {
        int p = nt * 16 + a0;
        bool valid = p < NPAIR;
        if (!valid) p = 0;
        // closed-form pair decode: i = floor((39 - sqrt(1521-8p))/2), fixup +-1
        int i = (int)((39.0f - sqrtf((float)(1521 - 8 * p))) * 0.5f);
        int t  = (i * (39 - i)) >> 1;
        int t1 = ((i + 1) * (38 - i)) >> 1;
        if (p < t)        { --i; t = (i * (39 - i)) >> 1; }
        else if (p >= t1) { ++i; t = t1; }
        int j = p - t + i + 1;

        const char* bi = reinterpret_cast<const char*>(ew) + i * (ERS2*2);
        const char* bj = reinterpret_cast<const char*>(ew) + j * (ERS2*2);

        f32x4 acc0 = b1v[0];                // h + b1 folded into C-init
        f32x4 acc1 = b1v[1];
        f32x4 accs = (f32x4){0.f, 0.f, 0.f, 0.f};
        #pragma unroll
        for (int ks = 0; ks < 2; ++ks) {
            f16x8 ei = *reinterpret_cast<const f16x8*>(bi + ks*64 + g*16);  // 1 b128
            f16x8 ej = *reinterpret_cast<const f16x8*>(bj + ks*64 + g*16);  // 1 b128
            f16x8 pr = ei * ej;                                             // 4 pk_mul_f16
            acc0 = __builtin_amdgcn_mfma_f32_16x16x32_f16(aw[0][ks], pr, acc0, 0, 0, 0);
            acc1 = __builtin_amdgcn_mfma_f32_16x16x32_f16(aw[1][ks], pr, acc1, 0, 0, 0);
            accs = __builtin_amdgcn_mfma_f32_16x16x32_f16(apw[ks],   pr, accs, 0, 0, 0);
        }
        // logit for pair (nt,a0): in-lane over 8 att rows + 2 shuffles over g
        float tl = 0.f;
        #pragma unroll
        for (int r = 0; r < 4; ++r) {
            tl += fmaxf(acc0[r], 0.f) * w2v[0][r];
            tl += fmaxf(acc1[r], 0.f) * w2v[1][r];
        }
        tl += __shfl_xor(tl, 16);
        tl += __shfl_xor(tl, 32);
        float w = valid ? __expf(tl) : 0.f;
        num = fmaf(w, accs[0], num);        // accs[0]: s_p on g==0 lanes, 0 elsewhere
        den += w;
    }

    // ---- reduce num/den across a0 (g==0 group carries num; den replicated) ----
    num += __shfl_xor(num, 1);  den += __shfl_xor(den, 1);
    num += __shfl_xor(num, 2);  den += __shfl_xor(den, 2);
    num += __shfl_xor(num, 4);  den += __shfl_xor(den, 4);
    num += __shfl_xor(num, 8);  den += __shfl_xor(den, 8);

    if (lane == 0)
        out[b] = num / den + fbv + gbv;
}

extern "C" void kernel_launch(void* const* d_in, const int* in_sizes, int n_in,
                              void* d_out, int out_size, void* d_ws, size_t ws_size,
                              hipStream_t stream)
{
    const int*   feats = (const int*)  d_in[0];
    const float* fvals = (const float*)d_in[1];
    const float* emb   = (const float*)d_in[2];
    const float* btab  = (const float*)d_in[3];
    const float* gb    = (const float*)d_in[4];
    const float* w1    = (const float*)d_in[5];
    const float* b1    = (const float*)d_in[6];
    const float* w2    = (const float*)d_in[7];
    const float* pw    = (const float*)d_in[8];
    float*       out   = (float*)d_out;

    const int B = in_sizes[0] / VDIM;
    afm_fwd<<<(B + 3) / 4, 256, 0, stream>>>(feats, fvals, emb, btab, gb,
                                             w1, b1, w2, pw, out, B);
}

// Round 10
// 28.350 us; speedup vs baseline: 3.2720x; 1.0284x over previous
//
#include <hip/hip_runtime.h>

#define VDIM 20
#define NPAIR 190
#define NT 12            // 12 pair-tiles of 16 (190 -> 192)
#define EMB 64
#define ERS2 72          // f16 row stride (144 B)

typedef __attribute__((ext_vector_type(8))) _Float16 f16x8;  // MFMA A/B frag (4 VGPR)
typedef __attribute__((ext_vector_type(4))) _Float16 f16x4;
typedef __attribute__((ext_vector_type(4))) float    f32x4;

__device__ __forceinline__ f16x8 pack8(f32x4 a, f32x4 b) {
    auto p0 = __builtin_amdgcn_cvt_pkrtz(a[0], a[1]);  // v_cvt_pkrtz_f16_f32
    auto p1 = __builtin_amdgcn_cvt_pkrtz(a[2], a[3]);
    auto p2 = __builtin_amdgcn_cvt_pkrtz(b[0], b[1]);
    auto p3 = __builtin_amdgcn_cvt_pkrtz(b[2], b[3]);
    f16x8 r;
    r[0] = p0[0]; r[1] = p0[1]; r[2] = p1[0]; r[3] = p1[1];
    r[4] = p2[0]; r[5] = p2[1]; r[6] = p3[0]; r[7] = p3[1];
    return r;
}

__global__ __launch_bounds__(256, 4)
void afm_fwd(const int* __restrict__ feats, const float* __restrict__ fvals,
             const float* __restrict__ emb, const float* __restrict__ btab,
             const float* __restrict__ gbias, const float* __restrict__ w1,
             const float* __restrict__ b1, const float* __restrict__ w2,
             const float* __restrict__ pw, float* __restrict__ out, int B)
{
    __shared__ __align__(16) _Float16 ls_e[8][VDIM * ERS2];  // 2 slabs per wave

    const int tid  = threadIdx.x;
    const int wv   = tid >> 6;
    const int lane = tid & 63;
    const int g    = lane >> 4;
    const int a0   = lane & 15;
    const int b0   = blockIdx.x * 8 + wv * 2;   // wave owns samples b0, b0+1
    const int b1s  = b0 + 1;
    if (b0 >= B) return;                        // wave-uniform; no barriers below

    // ---- features/values: lanes 0-19 sample0, lanes 32-51 sample1 ----
    int ff = 0; float vv = 0.f;
    {
        int r = lane & 31, s = lane >> 5, sb = b0 + s;
        if (r < VDIM && sb < B) { ff = feats[sb * VDIM + r]; vv = fvals[sb * VDIM + r]; }
    }

    // ---- A-frags in f16 from L2-hot tables (shared by both samples) ----
    f16x8 aw[2][2];                              // W1: row m=a0+16*mta, k=ks*32+g*8+e
    #pragma unroll
    for (int mta = 0; mta < 2; ++mta)
        #pragma unroll
        for (int ks = 0; ks < 2; ++ks) {
            const f32x4* wp = reinterpret_cast<const f32x4*>(
                                  w1 + (a0 + 16*mta) * EMB + ks*32 + g*8);
            aw[mta][ks] = pack8(wp[0], wp[1]);
        }
    f16x8 apw[2];                                // pred_w on row 0 -> s_p in C row 0
    {
        const f16x8 zz = {};
        #pragma unroll
        for (int ks = 0; ks < 2; ++ks) {
            const f32x4* pp = reinterpret_cast<const f32x4*>(pw + ks*32 + g*8);
            apw[ks] = (a0 == 0) ? pack8(pp[0], pp[1]) : zz;
        }
    }

    // ---- b1/w2 slices: att = mta*16 + g*4 + r ----
    f32x4 b1v[2], w2v[2];
    #pragma unroll
    for (int mta = 0; mta < 2; ++mta) {
        b1v[mta] = *reinterpret_cast<const f32x4*>(b1 + mta*16 + g*4);
        w2v[mta] = *reinterpret_cast<const f32x4*>(w2 + mta*16 + g*4);
    }

    // ---- first-order bias: per-half reduce (no xor 32) ----
    float fbv = ((lane & 31) < VDIM) ? btab[ff] * vv : 0.f;
    #pragma unroll
    for (int off = 16; off; off >>= 1) fbv += __shfl_xor(fbv, off);
    const float gbv = gbias[0];

    // ---- gather both samples: 5 passes x 4 rows x 2 slabs ----
    _Float16* ew0 = ls_e[wv * 2];
    _Float16* ew1 = ls_e[wv * 2 + 1];
    #pragma unroll
    for (int q = 0; q < 5; ++q) {
        int   row = q * 4 + g;
        int   fI0 = __shfl(ff, row);        float vI0 = __shfl(vv, row);
        int   fI1 = __shfl(ff, 32 + row);   float vI1 = __shfl(vv, 32 + row);
        f32x4 ev0 = reinterpret_cast<const f32x4*>(emb + (size_t)fI0 * EMB)[a0];
        f32x4 ev1 = reinterpret_cast<const f32x4*>(emb + (size_t)fI1 * EMB)[a0];
        auto h00 = __builtin_amdgcn_cvt_pkrtz(ev0[0] * vI0, ev0[1] * vI0);
        auto h01 = __builtin_amdgcn_cvt_pkrtz(ev0[2] * vI0, ev0[3] * vI0);
        auto h10 = __builtin_amdgcn_cvt_pkrtz(ev1[0] * vI1, ev1[1] * vI1);
        auto h11 = __builtin_amdgcn_cvt_pkrtz(ev1[2] * vI1, ev1[3] * vI1);
        f16x4 hv0; hv0[0]=h00[0]; hv0[1]=h00[1]; hv0[2]=h01[0]; hv0[3]=h01[1];
        f16x4 hv1; hv1[0]=h10[0]; hv1[1]=h10[1]; hv1[2]=h11[0]; hv1[3]=h11[1];
        *reinterpret_cast<f16x4*>(reinterpret_cast<char*>(ew0) + row*(ERS2*2) + a0*8) = hv0;
        *reinterpret_cast<f16x4*>(reinterpret_cast<char*>(ew1) + row*(ERS2*2) + a0*8) = hv1;
    }
    asm volatile("s_waitcnt lgkmcnt(0)" ::: "memory");   // DS in-order within wave
    __builtin_amdgcn_wave_barrier();

    // ---- main: 12 pair-tiles x 2 samples; softmax without max-subtract ----
    float num0 = 0.f, den0 = 0.f, num1 = 0.f, den1 = 0.f;
    #pragma unroll 1
    for (int nt = 0; nt < NT; ++nt) {
        int p = nt * 16 + a0;
        bool valid = p < NPAIR;
        if (!valid) p = 0;
        // closed-form pair decode (shared by both samples)
        int i = (int)((39.0f - sqrtf((float)(1521 - 8 * p))) * 0.5f);
        int t  = (i * (39 - i)) >> 1;
        int t1 = ((i + 1) * (38 - i)) >> 1;
        if (p < t)        { --i; t = (i * (39 - i)) >> 1; }
        else if (p >= t1) { ++i; t = t1; }
        int j = p - t + i + 1;
        const int oi = i * (ERS2 * 2), oj = j * (ERS2 * 2);

        f32x4 acc00 = b1v[0], acc01 = b1v[1], accs0 = (f32x4){0.f,0.f,0.f,0.f};
        f32x4 acc10 = b1v[0], acc11 = b1v[1], accs1 = (f32x4){0.f,0.f,0.f,0.f};
        #pragma unroll
        for (int ks = 0; ks < 2; ++ks) {
            const char* c0 = reinterpret_cast<const char*>(ew0);
            const char* c1 = reinterpret_cast<const char*>(ew1);
            f16x8 ei0 = *reinterpret_cast<const f16x8*>(c0 + oi + ks*64 + g*16);
            f16x8 ej0 = *reinterpret_cast<const f16x8*>(c0 + oj + ks*64 + g*16);
            f16x8 ei1 = *reinterpret_cast<const f16x8*>(c1 + oi + ks*64 + g*16);
            f16x8 ej1 = *reinterpret_cast<const f16x8*>(c1 + oj + ks*64 + g*16);
            f16x8 pr0 = ei0 * ej0;                       // v_pk_mul_f16 x4
            f16x8 pr1 = ei1 * ej1;
            acc00 = __builtin_amdgcn_mfma_f32_16x16x32_f16(aw[0][ks], pr0, acc00, 0, 0, 0);
            acc01 = __builtin_amdgcn_mfma_f32_16x16x32_f16(aw[1][ks], pr0, acc01, 0, 0, 0);
            accs0 = __builtin_amdgcn_mfma_f32_16x16x32_f16(apw[ks],   pr0, accs0, 0, 0, 0);
            acc10 = __builtin_amdgcn_mfma_f32_16x16x32_f16(aw[0][ks], pr1, acc10, 0, 0, 0);
            acc11 = __builtin_amdgcn_mfma_f32_16x16x32_f16(aw[1][ks], pr1, acc11, 0, 0, 0);
            accs1 = __builtin_amdgcn_mfma_f32_16x16x32_f16(apw[ks],   pr1, accs1, 0, 0, 0);
        }
        float tl0 = 0.f, tl1 = 0.f;
        #pragma unroll
        for (int r = 0; r < 4; ++r) {
            tl0 += fmaxf(acc00[r], 0.f) * w2v[0][r];
            tl0 += fmaxf(acc01[r], 0.f) * w2v[1][r];
            tl1 += fmaxf(acc10[r], 0.f) * w2v[0][r];
            tl1 += fmaxf(acc11[r], 0.f) * w2v[1][r];
        }
        tl0 += __shfl_xor(tl0, 16);  tl1 += __shfl_xor(tl1, 16);
        tl0 += __shfl_xor(tl0, 32);  tl1 += __shfl_xor(tl1, 32);
        float w0 = valid ? __expf(tl0) : 0.f;
        float w1x = valid ? __expf(tl1) : 0.f;
        num0 = fmaf(w0,  accs0[0], num0);  den0 += w0;   // accs[0]: s_p on g==0 lanes
        num1 = fmaf(w1x, accs1[0], num1);  den1 += w1x;
    }

    // ---- reduce across a0 (num on g==0 lanes; den replicated over g) ----
    #pragma unroll
    for (int off = 8; off; off >>= 1) {
        num0 += __shfl_xor(num0, off);  den0 += __shfl_xor(den0, off);
        num1 += __shfl_xor(num1, off);  den1 += __shfl_xor(den1, off);
    }
    float fb1 = __shfl(fbv, 32);
    if (lane == 0) {
        out[b0] = num0 / den0 + fbv + gbv;
        if (b1s < B) out[b1s] = num1 / den1 + fb1 + gbv;
    }
}

extern "C" void kernel_launch(void* const* d_in, const int* in_sizes, int n_in,
                              void* d_out, int out_size, void* d_ws, size_t ws_size,
                              hipStream_t stream)
{
    const int*   feats = (const int*)  d_in[0];
    const float* fvals = (const float*)d_in[1];
    const float* emb   = (const float*)d_in[2];
    const float* btab  = (const float*)d_in[3];
    const float* gb    = (const float*)d_in[4];
    const float* w1    = (const float*)d_in[5];
    const float* b1    = (const float*)d_in[6];
    const float* w2    = (const float*)d_in[7];
    const float* pw    = (const float*)d_in[8];
    float*       out   = (float*)d_out;

    const int B = in_sizes[0] / VDIM;
    afm_fwd<<<(B + 7) / 8, 256, 0, stream>>>(feats, fvals, emb, btab, gb,
                                             w1, b1, w2, pw, out, B);
}

// Round 11
// 27.988 us; speedup vs baseline: 3.3143x; 1.0129x over previous
//
#include <hip/hip_runtime.h>

#define VDIM 20
#define NPAIR 190
#define NT 12            // 12 pair-tiles of 16 (190 -> 192)
#define EMB 64
#define ERS2 72          // f16 row stride (144 B)

typedef __attribute__((ext_vector_type(8))) _Float16 f16x8;  // MFMA A/B frag (4 VGPR)
typedef __attribute__((ext_vector_type(4))) _Float16 f16x4;
typedef __attribute__((ext_vector_type(4))) float    f32x4;

__device__ __forceinline__ f16x8 pack8(f32x4 a, f32x4 b) {
    auto p0 = __builtin_amdgcn_cvt_pkrtz(a[0], a[1]);  // v_cvt_pkrtz_f16_f32
    auto p1 = __builtin_amdgcn_cvt_pkrtz(a[2], a[3]);
    auto p2 = __builtin_amdgcn_cvt_pkrtz(b[0], b[1]);
    auto p3 = __builtin_amdgcn_cvt_pkrtz(b[2], b[3]);
    f16x8 r;
    r[0] = p0[0]; r[1] = p0[1]; r[2] = p1[0]; r[3] = p1[1];
    r[4] = p2[0]; r[5] = p2[1]; r[6] = p3[0]; r[7] = p3[1];
    return r;
}

__global__ __launch_bounds__(256, 3)   // R11: VGPR cap ~170 (was 4 -> cap 128) — spill test
void afm_fwd(const int* __restrict__ feats, const float* __restrict__ fvals,
             const float* __restrict__ emb, const float* __restrict__ btab,
             const float* __restrict__ gbias, const float* __restrict__ w1,
             const float* __restrict__ b1, const float* __restrict__ w2,
             const float* __restrict__ pw, float* __restrict__ out, int B)
{
    __shared__ __align__(16) _Float16 ls_e[8][VDIM * ERS2];  // 2 slabs per wave

    const int tid  = threadIdx.x;
    const int wv   = tid >> 6;
    const int lane = tid & 63;
    const int g    = lane >> 4;
    const int a0   = lane & 15;
    const int b0   = blockIdx.x * 8 + wv * 2;   // wave owns samples b0, b0+1
    const int b1s  = b0 + 1;
    if (b0 >= B) return;                        // wave-uniform; no barriers below

    // ---- features/values: lanes 0-19 sample0, lanes 32-51 sample1 ----
    int ff = 0; float vv = 0.f;
    {
        int r = lane & 31, s = lane >> 5, sb = b0 + s;
        if (r < VDIM && sb < B) { ff = feats[sb * VDIM + r]; vv = fvals[sb * VDIM + r]; }
    }

    // ---- A-frags in f16 from L2-hot tables (shared by both samples) ----
    f16x8 aw[2][2];                              // W1: row m=a0+16*mta, k=ks*32+g*8+e
    #pragma unroll
    for (int mta = 0; mta < 2; ++mta)
        #pragma unroll
        for (int ks = 0; ks < 2; ++ks) {
            const f32x4* wp = reinterpret_cast<const f32x4*>(
                                  w1 + (a0 + 16*mta) * EMB + ks*32 + g*8);
            aw[mta][ks] = pack8(wp[0], wp[1]);
        }
    f16x8 apw[2];                                // pred_w on row 0 -> s_p in C row 0
    {
        const f16x8 zz = {};
        #pragma unroll
        for (int ks = 0; ks < 2; ++ks) {
            const f32x4* pp = reinterpret_cast<const f32x4*>(pw + ks*32 + g*8);
            apw[ks] = (a0 == 0) ? pack8(pp[0], pp[1]) : zz;
        }
    }

    // ---- b1/w2 slices: att = mta*16 + g*4 + r ----
    f32x4 b1v[2], w2v[2];
    #pragma unroll
    for (int mta = 0; mta < 2; ++mta) {
        b1v[mta] = *reinterpret_cast<const f32x4*>(b1 + mta*16 + g*4);
        w2v[mta] = *reinterpret_cast<const f32x4*>(w2 + mta*16 + g*4);
    }

    // ---- first-order bias: per-half reduce (no xor 32) ----
    float fbv = ((lane & 31) < VDIM) ? btab[ff] * vv : 0.f;
    #pragma unroll
    for (int off = 16; off; off >>= 1) fbv += __shfl_xor(fbv, off);
    const float gbv = gbias[0];

    // ---- gather both samples: 5 passes x 4 rows x 2 slabs ----
    _Float16* ew0 = ls_e[wv * 2];
    _Float16* ew1 = ls_e[wv * 2 + 1];
    #pragma unroll
    for (int q = 0; q < 5; ++q) {
        int   row = q * 4 + g;
        int   fI0 = __shfl(ff, row);        float vI0 = __shfl(vv, row);
        int   fI1 = __shfl(ff, 32 + row);   float vI1 = __shfl(vv, 32 + row);
        f32x4 ev0 = reinterpret_cast<const f32x4*>(emb + (size_t)fI0 * EMB)[a0];
        f32x4 ev1 = reinterpret_cast<const f32x4*>(emb + (size_t)fI1 * EMB)[a0];
        auto h00 = __builtin_amdgcn_cvt_pkrtz(ev0[0] * vI0, ev0[1] * vI0);
        auto h01 = __builtin_amdgcn_cvt_pkrtz(ev0[2] * vI0, ev0[3] * vI0);
        auto h10 = __builtin_amdgcn_cvt_pkrtz(ev1[0] * vI1, ev1[1] * vI1);
        auto h11 = __builtin_amdgcn_cvt_pkrtz(ev1[2] * vI1, ev1[3] * vI1);
        f16x4 hv0; hv0[0]=h00[0]; hv0[1]=h00[1]; hv0[2]=h01[0]; hv0[3]=h01[1];
        f16x4 hv1; hv1[0]=h10[0]; hv1[1]=h10[1]; hv1[2]=h11[0]; hv1[3]=h11[1];
        *reinterpret_cast<f16x4*>(reinterpret_cast<char*>(ew0) + row*(ERS2*2) + a0*8) = hv0;
        *reinterpret_cast<f16x4*>(reinterpret_cast<char*>(ew1) + row*(ERS2*2) + a0*8) = hv1;
    }
    asm volatile("s_waitcnt lgkmcnt(0)" ::: "memory");   // DS in-order within wave
    __builtin_amdgcn_wave_barrier();

    // ---- main: 12 pair-tiles x 2 samples; softmax without max-subtract ----
    float num0 = 0.f, den0 = 0.f, num1 = 0.f, den1 = 0.f;
    #pragma unroll 1
    for (int nt = 0; nt < NT; ++nt) {
        int p = nt * 16 + a0;
        bool valid = p < NPAIR;
        if (!valid) p = 0;
        // closed-form pair decode (shared by both samples)
        int i = (int)((39.0f - sqrtf((float)(1521 - 8 * p))) * 0.5f);
        int t  = (i * (39 - i)) >> 1;
        int t1 = ((i + 1) * (38 - i)) >> 1;
        if (p < t)        { --i; t = (i * (39 - i)) >> 1; }
        else if (p >= t1) { ++i; t = t1; }
        int j = p - t + i + 1;
        const int oi = i * (ERS2 * 2), oj = j * (ERS2 * 2);

        f32x4 acc00 = b1v[0], acc01 = b1v[1], accs0 = (f32x4){0.f,0.f,0.f,0.f};
        f32x4 acc10 = b1v[0], acc11 = b1v[1], accs1 = (f32x4){0.f,0.f,0.f,0.f};
        #pragma unroll
        for (int ks = 0; ks < 2; ++ks) {
            const char* c0 = reinterpret_cast<const char*>(ew0);
            const char* c1 = reinterpret_cast<const char*>(ew1);
            f16x8 ei0 = *reinterpret_cast<const f16x8*>(c0 + oi + ks*64 + g*16);
            f16x8 ej0 = *reinterpret_cast<const f16x8*>(c0 + oj + ks*64 + g*16);
            f16x8 ei1 = *reinterpret_cast<const f16x8*>(c1 + oi + ks*64 + g*16);
            f16x8 ej1 = *reinterpret_cast<const f16x8*>(c1 + oj + ks*64 + g*16);
            f16x8 pr0 = ei0 * ej0;                       // v_pk_mul_f16 x4
            f16x8 pr1 = ei1 * ej1;
            acc00 = __builtin_amdgcn_mfma_f32_16x16x32_f16(aw[0][ks], pr0, acc00, 0, 0, 0);
            acc01 = __builtin_amdgcn_mfma_f32_16x16x32_f16(aw[1][ks], pr0, acc01, 0, 0, 0);
            accs0 = __builtin_amdgcn_mfma_f32_16x16x32_f16(apw[ks],   pr0, accs0, 0, 0, 0);
            acc10 = __builtin_amdgcn_mfma_f32_16x16x32_f16(aw[0][ks], pr1, acc10, 0, 0, 0);
            acc11 = __builtin_amdgcn_mfma_f32_16x16x32_f16(aw[1][ks], pr1, acc11, 0, 0, 0);
            accs1 = __builtin_amdgcn_mfma_f32_16x16x32_f16(apw[ks],   pr1, accs1, 0, 0, 0);
        }
        float tl0 = 0.f, tl1 = 0.f;
        #pragma unroll
        for (int r = 0; r < 4; ++r) {
            tl0 += fmaxf(acc00[r], 0.f) * w2v[0][r];
            tl0 += fmaxf(acc01[r], 0.f) * w2v[1][r];
            tl1 += fmaxf(acc10[r], 0.f) * w2v[0][r];
            tl1 += fmaxf(acc11[r], 0.f) * w2v[1][r];
        }
        tl0 += __shfl_xor(tl0, 16);  tl1 += __shfl_xor(tl1, 16);
        tl0 += __shfl_xor(tl0, 32);  tl1 += __shfl_xor(tl1, 32);
        float w0 = valid ? __expf(tl0) : 0.f;
        float w1x = valid ? __expf(tl1) : 0.f;
        num0 = fmaf(w0,  accs0[0], num0);  den0 += w0;   // accs[0]: s_p on g==0 lanes
        num1 = fmaf(w1x, accs1[0], num1);  den1 += w1x;
    }

    // ---- reduce across a0 (num on g==0 lanes; den replicated over g) ----
    #pragma unroll
    for (int off = 8; off; off >>= 1) {
        num0 += __shfl_xor(num0, off);  den0 += __shfl_xor(den0, off);
        num1 += __shfl_xor(num1, off);  den1 += __shfl_xor(den1, off);
    }
    float fb1 = __shfl(fbv, 32);
    if (lane == 0) {
        out[b0] = num0 / den0 + fbv + gbv;
        if (b1s < B) out[b1s] = num1 / den1 + fb1 + gbv;
    }
}

extern "C" void kernel_launch(void* const* d_in, const int* in_sizes, int n_in,
                              void* d_out, int out_size, void* d_ws, size_t ws_size,
                              hipStream_t stream)
{
    const int*   feats = (const int*)  d_in[0];
    const float* fvals = (const float*)d_in[1];
    const float* emb   = (const float*)d_in[2];
    const float* btab  = (const float*)d_in[3];
    const float* gb    = (const float*)d_in[4];
    const float* w1    = (const float*)d_in[5];
    const float* b1    = (const float*)d_in[6];
    const float* w2    = (const float*)d_in[7];
    const float* pw    = (const float*)d_in[8];
    float*       out   = (float*)d_out;

    const int B = in_sizes[0] / VDIM;
    afm_fwd<<<(B + 7) / 8, 256, 0, stream>>>(feats, fvals, emb, btab, gb,
                                             w1, b1, w2, pw, out, B);
}